// Round 5
// baseline (515.381 us; speedup 1.0000x reference)
//
#include <hip/hip_runtime.h>
#include <hip/hip_fp16.h>
#include <cstdint>

#define FIN  65536
#define NBLK 512

// ws float-offsets (counters isolated in their own cachelines)
#define CNT_F   0        // 3 barrier counters (uint), memset to 0 pre-launch
#define SPART_F 64       // 256: per-block absmax(x) partials
#define WABS_F  320      // 256: per-row absmax of dense_w
#define SFW_F   576      // 64: conv per-channel weight scale
#define WINT_F  640      // 1728: conv w_int
#define HPART_F 2368     // 512: per-block max(h) partials
#define H16_B   16384    // byte: f16 h buffer [256][65536] = 32 MB
#define PART_B  33570816 // byte: GEMM partials [64 slices][8 tiles][8192] f32 = 16 MB
// total ws usage ~50.3 MB (< 53.4 MB proven available in R2)

typedef _Float16 half8 __attribute__((ext_vector_type(8)));
typedef _Float16 half2v __attribute__((ext_vector_type(2)));
typedef float    floatx4 __attribute__((ext_vector_type(4)));
typedef unsigned short u16;

__device__ inline float blockMax(float v) {
    #pragma unroll
    for (int off = 32; off; off >>= 1) v = fmaxf(v, __shfl_down(v, off));
    __shared__ float sm[4];
    const int lane = threadIdx.x & 63, w = threadIdx.x >> 6;
    if (lane == 0) sm[w] = v;
    __syncthreads();
    float m = fmaxf(fmaxf(sm[0], sm[1]), fmaxf(sm[2], sm[3]));
    __syncthreads();
    return m;
}

// device-scope grid barrier: one-shot counter per barrier instance.
// Safe: grid=512, launch_bounds(256,2), LDS 29KB -> 2 blocks/CU co-resident.
__device__ inline void gbar(unsigned* c, unsigned target) {
    __syncthreads();
    if (threadIdx.x == 0) {
        __threadfence();  // release: drain vmem writes (agent scope)
        __hip_atomic_fetch_add(c, 1u, __ATOMIC_ACQ_REL, __HIP_MEMORY_SCOPE_AGENT);
        while (__hip_atomic_load(c, __ATOMIC_ACQUIRE, __HIP_MEMORY_SCOPE_AGENT) < target)
            __builtin_amdgcn_s_sleep(1);
        __threadfence();  // acquire: invalidate caches before phase reads
    }
    __syncthreads();
}

__global__ __launch_bounds__(256, 2) void mega(const float* __restrict__ x,
                                               const float* __restrict__ cw,
                                               const float* __restrict__ cb,
                                               const float* __restrict__ dw,
                                               const float* __restrict__ db,
                                               float* __restrict__ out,
                                               float* __restrict__ ws) {
    const int b = blockIdx.x, tid = threadIdx.x;
    unsigned* cnt = (unsigned*)ws;

    __shared__ __align__(16) _Float16 As[128][72];   // 18.4 KB
    __shared__ __align__(16) _Float16 Bs[64][72];    //  9.2 KB
    __shared__ float scB[64];
    __shared__ float bsfL[64], bintL[64];
    __shared__ float red2[128];

    u16* h16 = (u16*)((char*)ws + H16_B);

    // ======== Phase 1: absmax(x) partials; dw row absmax; conv-w quant ========
    if (b < 256) {
        const float4* x4 = (const float4*)x;
        float m = 0.f;
        #pragma unroll
        for (int j = 0; j < 12; j++) {
            float4 v = x4[b * 3072 + j * 256 + tid];
            m = fmaxf(m, fmaxf(fmaxf(fabsf(v.x), fabsf(v.y)), fmaxf(fabsf(v.z), fabsf(v.w))));
        }
        float bm = blockMax(m);
        if (tid == 0) ws[SPART_F + b] = bm;
    } else {
        const int row = b - 256;
        const float4* r4 = (const float4*)(dw + (size_t)row * FIN);
        float m = 0.f;
        for (int j = 0; j < 64; j++) {
            float4 v = r4[j * 256 + tid];
            m = fmaxf(m, fmaxf(fmaxf(fabsf(v.x), fabsf(v.y)), fmaxf(fabsf(v.z), fabsf(v.w))));
        }
        float bm = blockMax(m);
        if (tid == 0) ws[WABS_F + row] = bm;
        if (b == 511 && tid < 64) {
            float wv[27]; float mm = 0.f;
            #pragma unroll
            for (int i = 0; i < 27; i++) { wv[i] = cw[tid * 27 + i]; mm = fmaxf(mm, fabsf(wv[i])); }
            const float sfw = fmaxf(mm, 1e-8f) / 127.0f;
            ws[SFW_F + tid] = sfw;
            #pragma unroll
            for (int i = 0; i < 27; i++)
                ws[WINT_F + tid * 27 + i] = fminf(127.f, fmaxf(-127.f, rintf(wv[i] / sfw)));
        }
    }
    gbar(cnt + 0, NBLK);

    // ======== Phase 2: conv 3x3 s2 p1 + relu + f16 store; max(h) partials ========
    const float p_sf = fmaxf(blockMax(ws[SPART_F + tid]), 1e-8f) / 32767.0f;
    const float inv_p = 1.0f / p_sf;
    if (tid < 64) {
        const float bsf = p_sf * ws[SFW_F + tid];
        bsfL[tid] = bsf;
        bintL[tid] = rintf(cb[tid] / bsf);
    }
    __syncthreads();

    float mx = 0.f;
    {
        const int ox = tid & 31;
        const int ch = __builtin_amdgcn_readfirstlane((tid >> 6) & 1);
        const float* wr = ws + WINT_F + ch * 864;
        #pragma unroll
        for (int u = 0; u < 4; u++) {
            const int g = b * 4 + u;
            const int imgb = g >> 3;
            const int oy = (g & 7) * 4 + ((tid >> 7) << 1) + ((tid >> 5) & 1);
            const float* xb = x + (size_t)imgb * (3 * 64 * 64);
            float xs[27];
            #pragma unroll
            for (int ci = 0; ci < 3; ci++)
                #pragma unroll
                for (int ky = 0; ky < 3; ky++) {
                    const int iy = 2 * oy - 1 + ky;
                    const bool yok = ((unsigned)iy < 64u);
                    #pragma unroll
                    for (int kx = 0; kx < 3; kx++) {
                        const int ix = 2 * ox - 1 + kx;
                        float v = (yok && ((unsigned)ix < 64u)) ? xb[(ci * 64 + iy) * 64 + ix] : 0.f;
                        xs[ci * 9 + ky * 3 + kx] = fminf(32767.f, fmaxf(-32767.f, rintf(v * inv_p)));
                    }
                }
            float acc2[32];
            #pragma unroll
            for (int c = 0; c < 32; c++) {
                float a = 0.f;
                #pragma unroll
                for (int k = 0; k < 27; k++) a = fmaf(xs[k], wr[c * 27 + k], a);
                acc2[c] = a;
            }
            const size_t base = (size_t)imgb * FIN + (size_t)ch * 32768 + oy * 32 + ox;
            #pragma unroll
            for (int c = 0; c < 32; c++) {
                const int co = ch * 32 + c;
                float h = fmaxf((acc2[c] + bintL[co]) * bsfL[co], 0.f);
                mx = fmaxf(mx, h);
                h16[base + (size_t)c * 1024] = __half_as_ushort(__float2half(h));
            }
        }
    }
    {
        float bm = blockMax(mx);
        if (tid == 0) ws[HPART_F + b] = bm;
    }
    gbar(cnt + 1, NBLK);

    // ======== Phase 3: GEMM 8 tiles(128x64) x 64 K-slices, partial store ========
    const float max_h = blockMax(fmaxf(ws[HPART_F + tid], ws[HPART_F + 256 + tid]));
    const float p2 = fmaxf(max_h, 1e-8f) / 1023.0f;
    const float inv_p2 = 1023.0f / fmaxf(max_h, 1e-8f);

    const int slice = b >> 3, tile = b & 7;
    const int tm = (tile >> 2) * 128, tn = (tile & 3) * 64;
    const int k0 = slice * 1024;

    if (tid < 64) scB[tid] = 127.0f / fmaxf(ws[WABS_F + tn + tid], 1e-8f);
    __syncthreads();

    const _Float16 invh = (_Float16)inv_p2;
    const half2v inv2  = {invh, invh};
    const half2v m1024 = {(_Float16)1024.0f, (_Float16)1024.0f};
    const half2v m1536 = {(_Float16)1536.0f, (_Float16)1536.0f};
    const half2v c1023 = {(_Float16)1023.0f, (_Float16)1023.0f};
    const half2v c127  = {(_Float16)127.0f, (_Float16)127.0f};
    const half2v cn127 = {(_Float16)-127.0f, (_Float16)-127.0f};

    floatx4 acc[4][2];
    const floatx4 zz = {0.f, 0.f, 0.f, 0.f};
    #pragma unroll
    for (int i = 0; i < 4; i++) { acc[i][0] = zz; acc[i][1] = zz; }

    const int wv = tid >> 6, lane = tid & 63;
    const int wm = (wv >> 1) * 64, wn = (wv & 1) * 32;
    const int lm = lane & 15, quad = lane >> 4;

    const int arow = tid >> 3, ac8 = tid & 7;   // A: 128 rows x 8 half8-chunks (+r*32)
    const int brow = tid >> 4, bc4 = tid & 15;  // B: 64 rows x 16 float4-chunks (+r*16)

    half8  Ar[4];
    float4 Br[4];
    auto loadA = [&](int kk) {
        #pragma unroll
        for (int r = 0; r < 4; r++)
            Ar[r] = *(const half8*)(h16 + (size_t)(tm + arow + r * 32) * FIN + k0 + kk * 64 + ac8 * 8);
    };
    auto loadB = [&](int kk) {
        #pragma unroll
        for (int r = 0; r < 4; r++)
            Br[r] = *(const float4*)(dw + (size_t)(tn + brow + r * 16) * FIN + k0 + kk * 64 + bc4 * 4);
    };
    loadA(0); loadB(0);

    for (int kk = 0; kk < 16; kk++) {
        // A requant: packed-f16 magic rounding (exact RNE-to-int in [1024,2048) ULP=1 zone)
        #pragma unroll
        for (int r = 0; r < 4; r++) {
            half2v* hp = (half2v*)&Ar[r];
            half2v q[4];
            #pragma unroll
            for (int j = 0; j < 4; j++) {
                half2v t = __builtin_elementwise_fma(hp[j], inv2, m1024) - m1024;
                q[j] = __builtin_elementwise_min(t, c1023);
            }
            *(half8*)&As[arow + r * 32][ac8 * 8] = *(half8*)q;
        }
        // B quant: f32 -> f16(RN) -> packed magic round + clamp +-127
        #pragma unroll
        for (int r = 0; r < 4; r++) {
            const _Float16 ish = (_Float16)scB[brow + r * 16];
            const half2v is2 = {ish, ish};
            half2v w01 = {(_Float16)Br[r].x, (_Float16)Br[r].y};
            half2v w23 = {(_Float16)Br[r].z, (_Float16)Br[r].w};
            half2v q01 = __builtin_elementwise_fma(w01, is2, m1536) - m1536;
            half2v q23 = __builtin_elementwise_fma(w23, is2, m1536) - m1536;
            q01 = __builtin_elementwise_min(__builtin_elementwise_max(q01, cn127), c127);
            q23 = __builtin_elementwise_min(__builtin_elementwise_max(q23, cn127), c127);
            half2v* bp = (half2v*)&Bs[brow + r * 16][bc4 * 4];
            bp[0] = q01; bp[1] = q23;
        }
        __syncthreads();
        if (kk < 15) { loadA(kk + 1); loadB(kk + 1); }  // fly under MFMA phase
        #pragma unroll
        for (int ks = 0; ks < 2; ks++) {
            half8 af[4], bf[2];
            #pragma unroll
            for (int mi = 0; mi < 4; mi++)
                af[mi] = *(const half8*)&As[wm + mi * 16 + lm][ks * 32 + quad * 8];
            #pragma unroll
            for (int ni = 0; ni < 2; ni++)
                bf[ni] = *(const half8*)&Bs[wn + ni * 16 + lm][ks * 32 + quad * 8];
            #pragma unroll
            for (int mi = 0; mi < 4; mi++)
                #pragma unroll
                for (int ni = 0; ni < 2; ni++)
                    acc[mi][ni] = __builtin_amdgcn_mfma_f32_16x16x32_f16(af[mi], bf[ni], acc[mi][ni], 0, 0, 0);
        }
        __syncthreads();
    }
    {
        float* part = (float*)((char*)ws + PART_B) + (size_t)b * 8192;
        #pragma unroll
        for (int mi = 0; mi < 4; mi++)
            #pragma unroll
            for (int ni = 0; ni < 2; ni++)
                #pragma unroll
                for (int r = 0; r < 4; r++) {
                    const int lmrow = wm + mi * 16 + quad * 4 + r;
                    const int lncol = wn + ni * 16 + lm;
                    part[lmrow * 64 + lncol] = acc[mi][ni][r];
                }
    }
    gbar(cnt + 2, NBLK);

    // ======== Phase 4: reduce 64 partials + bias + relu ========
    {
        const int o = b * 128 + (tid & 127);
        const int m = o >> 8, n = o & 255;
        const int grp = tid >> 7;
        const int tile4 = (m >> 7) * 4 + (n >> 6);
        const int loc = (m & 127) * 64 + (n & 63);
        const float* base = (const float*)((const char*)ws + PART_B) + (size_t)tile4 * 8192 + loc;
        float s = 0.f;
        #pragma unroll
        for (int j = 0; j < 32; j++) s += base[(size_t)(grp * 32 + j) * 65536];
        if (grp == 1) red2[tid & 127] = s;
        __syncthreads();
        if (grp == 0) {
            const float total = s + red2[tid];
            const float wsf = fmaxf(ws[WABS_F + n], 1e-8f) / 127.0f;
            const float bsf = p2 * wsf;
            const float bint = rintf(db[n] / bsf);
            out[o] = fmaxf(0.f, (total + bint) * bsf);
        }
    }
}

extern "C" void kernel_launch(void* const* d_in, const int* in_sizes, int n_in,
                              void* d_out, int out_size, void* d_ws, size_t ws_size,
                              hipStream_t stream) {
    (void)in_sizes; (void)n_in; (void)out_size; (void)ws_size;
    const float* x  = (const float*)d_in[0];
    const float* cw = (const float*)d_in[1];
    const float* cb = (const float*)d_in[2];
    const float* dw = (const float*)d_in[3];
    const float* db = (const float*)d_in[4];
    float* out = (float*)d_out;
    float* ws  = (float*)d_ws;

    // zero the barrier counters (ws is poisoned 0xAA before every timed launch)
    (void)hipMemsetAsync(d_ws, 0, 256, stream);
    mega<<<NBLK, 256, 0, stream>>>(x, cw, cb, dw, db, out, ws);
}

// Round 6
// 388.379 us; speedup vs baseline: 1.3270x; 1.3270x over previous
//
#include <hip/hip_runtime.h>
#include <hip/hip_fp16.h>
#include <cstdint>

#define FIN  65536
#define NBLK 512

// ws float-offsets (counters isolated in their own cachelines)
#define CNT_F   0        // 3 barrier counters (uint), memset to 0 pre-launch
#define SPART_F 64       // 512: per-block absmax(x) partials
#define WABS_F  576      // 512: per-(row,half) absmax of dense_w  [2*row+half]
#define SFW_F   1088     // 64: conv per-channel weight scale
#define WINT_F  1152     // 1728: conv w_int
#define HPART_F 2880     // 512: per-block max(h) partials
#define H16_B   16384    // byte: f16 h buffer [256][65536] = 32 MB
#define PART_B  33570816 // byte: GEMM partials [64 slices][8 tiles][8192] f32 = 16 MB

typedef _Float16 half8 __attribute__((ext_vector_type(8)));
typedef _Float16 half2v __attribute__((ext_vector_type(2)));
typedef float    floatx4 __attribute__((ext_vector_type(4)));
typedef unsigned short u16;

__device__ inline float blockMax(float v) {
    #pragma unroll
    for (int off = 32; off; off >>= 1) v = fmaxf(v, __shfl_down(v, off));
    __shared__ float sm[4];
    const int lane = threadIdx.x & 63, w = threadIdx.x >> 6;
    if (lane == 0) sm[w] = v;
    __syncthreads();
    float m = fmaxf(fmaxf(sm[0], sm[1]), fmaxf(sm[2], sm[3]));
    __syncthreads();
    return m;
}

// device-scope grid barrier. KEY FIX vs R5: spin with RELAXED loads (no
// per-iteration cache invalidate), single acquire fence after exit.
__device__ inline void gbar(unsigned* c, unsigned target) {
    __syncthreads();
    if (threadIdx.x == 0) {
        __threadfence();  // release: make prior writes agent-visible
        __hip_atomic_fetch_add(c, 1u, __ATOMIC_RELAXED, __HIP_MEMORY_SCOPE_AGENT);
        while (__hip_atomic_load(c, __ATOMIC_RELAXED, __HIP_MEMORY_SCOPE_AGENT) < target)
            __builtin_amdgcn_s_sleep(2);
        __threadfence();  // acquire: ONE invalidate before phase reads
    }
    __syncthreads();
}

__global__ __launch_bounds__(256, 2) void mega(const float* __restrict__ x,
                                               const float* __restrict__ cw,
                                               const float* __restrict__ cb,
                                               const float* __restrict__ dw,
                                               const float* __restrict__ db,
                                               float* __restrict__ out,
                                               float* __restrict__ ws) {
    const int b = blockIdx.x, tid = threadIdx.x;
    unsigned* cnt = (unsigned*)ws;

    __shared__ __align__(16) _Float16 As[128][72];   // 18.4 KB
    __shared__ __align__(16) _Float16 Bs[64][72];    //  9.2 KB
    __shared__ float scB[64];
    __shared__ float bsfL[64], bintL[64];
    __shared__ float red2[128];

    u16* h16 = (u16*)((char*)ws + H16_B);

    // ======== Phase 1 (balanced): every block does half a dw row + x slice ====
    {
        // dw half-row: row = b>>1, half = b&1 (128 KB each)
        const int row = b >> 1, half = b & 1;
        const float4* r4 = (const float4*)(dw + (size_t)row * FIN) + half * 8192;
        float m = 0.f;
        #pragma unroll 4
        for (int j = 0; j < 32; j++) {
            float4 v = r4[j * 256 + tid];
            m = fmaxf(m, fmaxf(fmaxf(fabsf(v.x), fabsf(v.y)), fmaxf(fabsf(v.z), fabsf(v.w))));
        }
        float bm = blockMax(m);
        if (tid == 0) ws[WABS_F + b] = bm;  // [2*row+half]
        // x slice: 512 blocks x 6 float4-iters
        const float4* x4 = (const float4*)x;
        float mx2 = 0.f;
        #pragma unroll
        for (int j = 0; j < 6; j++) {
            float4 v = x4[b * 1536 + j * 256 + tid];
            mx2 = fmaxf(mx2, fmaxf(fmaxf(fabsf(v.x), fabsf(v.y)), fmaxf(fabsf(v.z), fabsf(v.w))));
        }
        float bmx = blockMax(mx2);
        if (tid == 0) ws[SPART_F + b] = bmx;
        if (b == 511 && tid < 64) {
            float wv[27]; float mm = 0.f;
            #pragma unroll
            for (int i = 0; i < 27; i++) { wv[i] = cw[tid * 27 + i]; mm = fmaxf(mm, fabsf(wv[i])); }
            const float sfw = fmaxf(mm, 1e-8f) / 127.0f;
            ws[SFW_F + tid] = sfw;
            #pragma unroll
            for (int i = 0; i < 27; i++)
                ws[WINT_F + tid * 27 + i] = fminf(127.f, fmaxf(-127.f, rintf(wv[i] / sfw)));
        }
    }
    gbar(cnt + 0, NBLK);

    // ======== Phase 2: conv 3x3 s2 p1 + relu + f16 store; max(h) partials ========
    const float p_sf = fmaxf(blockMax(fmaxf(ws[SPART_F + tid], ws[SPART_F + 256 + tid])),
                             1e-8f) / 32767.0f;
    const float inv_p = 1.0f / p_sf;
    if (tid < 64) {
        const float bsf = p_sf * ws[SFW_F + tid];
        bsfL[tid] = bsf;
        bintL[tid] = rintf(cb[tid] / bsf);
    }
    __syncthreads();

    float mx = 0.f;
    {
        const int ox = tid & 31;
        const int ch = __builtin_amdgcn_readfirstlane((tid >> 6) & 1);
        const float* wr = ws + WINT_F + ch * 864;
        #pragma unroll
        for (int u = 0; u < 4; u++) {
            const int g = b * 4 + u;
            const int imgb = g >> 3;
            const int oy = (g & 7) * 4 + ((tid >> 7) << 1) + ((tid >> 5) & 1);
            const float* xb = x + (size_t)imgb * (3 * 64 * 64);
            float xs[27];
            #pragma unroll
            for (int ci = 0; ci < 3; ci++)
                #pragma unroll
                for (int ky = 0; ky < 3; ky++) {
                    const int iy = 2 * oy - 1 + ky;
                    const bool yok = ((unsigned)iy < 64u);
                    #pragma unroll
                    for (int kx = 0; kx < 3; kx++) {
                        const int ix = 2 * ox - 1 + kx;
                        float v = (yok && ((unsigned)ix < 64u)) ? xb[(ci * 64 + iy) * 64 + ix] : 0.f;
                        xs[ci * 9 + ky * 3 + kx] = fminf(32767.f, fmaxf(-32767.f, rintf(v * inv_p)));
                    }
                }
            float acc2[32];
            #pragma unroll
            for (int c = 0; c < 32; c++) {
                float a = 0.f;
                #pragma unroll
                for (int k = 0; k < 27; k++) a = fmaf(xs[k], wr[c * 27 + k], a);
                acc2[c] = a;
            }
            const size_t base = (size_t)imgb * FIN + (size_t)ch * 32768 + oy * 32 + ox;
            #pragma unroll
            for (int c = 0; c < 32; c++) {
                const int co = ch * 32 + c;
                float h = fmaxf((acc2[c] + bintL[co]) * bsfL[co], 0.f);
                mx = fmaxf(mx, h);
                h16[base + (size_t)c * 1024] = __half_as_ushort(__float2half(h));
            }
        }
    }
    {
        float bm = blockMax(mx);
        if (tid == 0) ws[HPART_F + b] = bm;
    }
    gbar(cnt + 1, NBLK);

    // ======== Phase 3: GEMM 8 tiles(128x64) x 64 K-slices, partial store ========
    const float max_h = blockMax(fmaxf(ws[HPART_F + tid], ws[HPART_F + 256 + tid]));
    const float p2 = fmaxf(max_h, 1e-8f) / 1023.0f;
    const float inv_p2 = 1023.0f / fmaxf(max_h, 1e-8f);

    const int slice = b >> 3, tile = b & 7;
    const int tm = (tile >> 2) * 128, tn = (tile & 3) * 64;
    const int k0 = slice * 1024;

    if (tid < 64) {
        const int row = tn + tid;
        const float am = fmaxf(fmaxf(ws[WABS_F + 2 * row], ws[WABS_F + 2 * row + 1]), 1e-8f);
        scB[tid] = 127.0f / am;
    }
    __syncthreads();

    const _Float16 invh = (_Float16)inv_p2;
    const half2v inv2  = {invh, invh};
    const half2v m1024 = {(_Float16)1024.0f, (_Float16)1024.0f};
    const half2v m1536 = {(_Float16)1536.0f, (_Float16)1536.0f};
    const half2v c1023 = {(_Float16)1023.0f, (_Float16)1023.0f};
    const half2v c127  = {(_Float16)127.0f, (_Float16)127.0f};
    const half2v cn127 = {(_Float16)-127.0f, (_Float16)-127.0f};

    floatx4 acc[4][2];
    const floatx4 zz = {0.f, 0.f, 0.f, 0.f};
    #pragma unroll
    for (int i = 0; i < 4; i++) { acc[i][0] = zz; acc[i][1] = zz; }

    const int wv = tid >> 6, lane = tid & 63;
    const int wm = (wv >> 1) * 64, wn = (wv & 1) * 32;
    const int lm = lane & 15, quad = lane >> 4;

    const int arow = tid >> 3, ac8 = tid & 7;   // A: 128 rows x 8 half8-chunks (+r*32)
    const int brow = tid >> 4, bc4 = tid & 15;  // B: 64 rows x 16 float4-chunks (+r*16)

    half8  Ar[4];
    float4 Br[4];
    auto loadA = [&](int kk) {
        #pragma unroll
        for (int r = 0; r < 4; r++)
            Ar[r] = *(const half8*)(h16 + (size_t)(tm + arow + r * 32) * FIN + k0 + kk * 64 + ac8 * 8);
    };
    auto loadB = [&](int kk) {
        #pragma unroll
        for (int r = 0; r < 4; r++)
            Br[r] = *(const float4*)(dw + (size_t)(tn + brow + r * 16) * FIN + k0 + kk * 64 + bc4 * 4);
    };
    loadA(0); loadB(0);

    for (int kk = 0; kk < 16; kk++) {
        // A requant: packed-f16 magic rounding (exact RNE-to-int in [1024,2048))
        #pragma unroll
        for (int r = 0; r < 4; r++) {
            half2v* hp = (half2v*)&Ar[r];
            half2v q[4];
            #pragma unroll
            for (int j = 0; j < 4; j++) {
                half2v t = __builtin_elementwise_fma(hp[j], inv2, m1024) - m1024;
                q[j] = __builtin_elementwise_min(t, c1023);
            }
            *(half8*)&As[arow + r * 32][ac8 * 8] = *(half8*)q;
        }
        // B quant: f32 -> f16(RN) -> packed magic round + clamp +-127
        #pragma unroll
        for (int r = 0; r < 4; r++) {
            const _Float16 ish = (_Float16)scB[brow + r * 16];
            const half2v is2 = {ish, ish};
            half2v w01 = {(_Float16)Br[r].x, (_Float16)Br[r].y};
            half2v w23 = {(_Float16)Br[r].z, (_Float16)Br[r].w};
            half2v q01 = __builtin_elementwise_fma(w01, is2, m1536) - m1536;
            half2v q23 = __builtin_elementwise_fma(w23, is2, m1536) - m1536;
            q01 = __builtin_elementwise_min(__builtin_elementwise_max(q01, cn127), c127);
            q23 = __builtin_elementwise_min(__builtin_elementwise_max(q23, cn127), c127);
            half2v* bp = (half2v*)&Bs[brow + r * 16][bc4 * 4];
            bp[0] = q01; bp[1] = q23;
        }
        __syncthreads();
        if (kk < 15) { loadA(kk + 1); loadB(kk + 1); }  // fly under MFMA phase
        #pragma unroll
        for (int ks = 0; ks < 2; ks++) {
            half8 af[4], bf[2];
            #pragma unroll
            for (int mi = 0; mi < 4; mi++)
                af[mi] = *(const half8*)&As[wm + mi * 16 + lm][ks * 32 + quad * 8];
            #pragma unroll
            for (int ni = 0; ni < 2; ni++)
                bf[ni] = *(const half8*)&Bs[wn + ni * 16 + lm][ks * 32 + quad * 8];
            #pragma unroll
            for (int mi = 0; mi < 4; mi++)
                #pragma unroll
                for (int ni = 0; ni < 2; ni++)
                    acc[mi][ni] = __builtin_amdgcn_mfma_f32_16x16x32_f16(af[mi], bf[ni], acc[mi][ni], 0, 0, 0);
        }
        __syncthreads();
    }
    {
        float* part = (float*)((char*)ws + PART_B) + (size_t)b * 8192;
        #pragma unroll
        for (int mi = 0; mi < 4; mi++)
            #pragma unroll
            for (int ni = 0; ni < 2; ni++)
                #pragma unroll
                for (int r = 0; r < 4; r++) {
                    const int lmrow = wm + mi * 16 + quad * 4 + r;
                    const int lncol = wn + ni * 16 + lm;
                    part[lmrow * 64 + lncol] = acc[mi][ni][r];
                }
    }
    gbar(cnt + 2, NBLK);

    // ======== Phase 4: reduce 64 partials + bias + relu ========
    {
        const int o = b * 128 + (tid & 127);
        const int m = o >> 8, n = o & 255;
        const int grp = tid >> 7;
        const int tile4 = (m >> 7) * 4 + (n >> 6);
        const int loc = (m & 127) * 64 + (n & 63);
        const float* base = (const float*)((const char*)ws + PART_B) + (size_t)tile4 * 8192 + loc;
        float s = 0.f;
        #pragma unroll
        for (int j = 0; j < 32; j++) s += base[(size_t)(grp * 32 + j) * 65536];
        if (grp == 1) red2[tid & 127] = s;
        __syncthreads();
        if (grp == 0) {
            const float total = s + red2[tid];
            const float am = fmaxf(fmaxf(ws[WABS_F + 2 * n], ws[WABS_F + 2 * n + 1]), 1e-8f);
            const float wsf = am / 127.0f;
            const float bsf = p2 * wsf;
            const float bint = rintf(db[n] / bsf);
            out[o] = fmaxf(0.f, (total + bint) * bsf);
        }
    }
}

extern "C" void kernel_launch(void* const* d_in, const int* in_sizes, int n_in,
                              void* d_out, int out_size, void* d_ws, size_t ws_size,
                              hipStream_t stream) {
    (void)in_sizes; (void)n_in; (void)out_size; (void)ws_size;
    const float* x  = (const float*)d_in[0];
    const float* cw = (const float*)d_in[1];
    const float* cb = (const float*)d_in[2];
    const float* dw = (const float*)d_in[3];
    const float* db = (const float*)d_in[4];
    float* out = (float*)d_out;
    float* ws  = (float*)d_ws;

    // zero the barrier counters (ws is poisoned 0xAA before every timed launch)
    (void)hipMemsetAsync(d_ws, 0, 256, stream);
    mega<<<NBLK, 256, 0, stream>>>(x, cw, cb, dw, db, out, ws);
}